// Round 5
// baseline (109.696 us; speedup 1.0000x reference)
//
#include <hip/hip_runtime.h>
#include <math.h>

// Problem constants
#define B_ 2
#define T_ 1024
#define D_ 512
#define H_ 8
#define DK_ 64
#define NBH_ 16          // B*H
#define C_ 32            // chunk length
#define G_ 32            // T/C chunks

#define PI_OVER_2T 0.00153398078788564122971808758949f  /* pi/2048 */

typedef float f32x4 __attribute__((ext_vector_type(4)));
typedef short s16x8 __attribute__((ext_vector_type(8)));

__device__ __forceinline__ ushort f2bf(float x) {
    unsigned u = __float_as_uint(x);
    unsigned r = (u + 0x7fffu + ((u >> 16) & 1u)) >> 16;   // RNE
    return (ushort)r;
}
__device__ __forceinline__ float bf2f(ushort u) {
    return __uint_as_float((unsigned)u << 16);
}

// async global->LDS, 16B/lane; LDS dest must be tid-contiguous (m104).
__device__ __forceinline__ void async16(void* lds, const void* g) {
    __builtin_amdgcn_global_load_lds(
        (const __attribute__((address_space(1))) void*)g,
        (__attribute__((address_space(3))) void*)lds, 16, 0, 0);
}

// ---------------------------------------------------------------------------
// Fused convert kernel (unchanged, passing).
// ---------------------------------------------------------------------------
__global__ __launch_bounds__(256) void k_conv(
    const float* __restrict__ x,
    const float* __restrict__ Wq, const float* __restrict__ Wk,
    const float* __restrict__ Wv, const float* __restrict__ Wg,
    const float* __restrict__ Wo,
    ushort* __restrict__ xb, ushort* __restrict__ WtAll)
{
    __shared__ float Ts[64][65];
    const int bx = blockIdx.x;
    const int tid = threadIdx.x;
    if (bx < 1024) {
        int i = (bx * 256 + tid) * 4;
        float4 v = *(const float4*)&x[i];
        ushort4 o;
        o.x = f2bf(v.x); o.y = f2bf(v.y); o.z = f2bf(v.z); o.w = f2bf(v.w);
        *(ushort4*)&xb[i] = o;
        return;
    }
    const int bid = bx - 1024;
    const int mi = bid >> 6;
    const int t64 = bid & 63;
    const float* __restrict__ W = (mi == 0) ? Wq : (mi == 1) ? Wk
                                 : (mi == 2) ? Wv : (mi == 3) ? Wg : Wo;
    const int tr = t64 >> 3, tc = t64 & 7;
#pragma unroll
    for (int p = 0; p < 4; p++) {
        int row = p * 16 + (tid >> 4);
        int c4 = (tid & 15) * 4;
        float4 v = *(const float4*)&W[(size_t)(tr * 64 + row) * 512 + tc * 64 + c4];
        Ts[row][c4 + 0] = v.x; Ts[row][c4 + 1] = v.y;
        Ts[row][c4 + 2] = v.z; Ts[row][c4 + 3] = v.w;
    }
    __syncthreads();
    const int nl = tid >> 2, kc = (tid & 3) * 16;
    ushort buf[16];
#pragma unroll
    for (int u = 0; u < 16; u++) buf[u] = f2bf(Ts[kc + u][nl]);
    ushort* dst = WtAll + (size_t)mi * 262144 + (size_t)(tc * 64 + nl) * 512
                  + tr * 64 + kc;
    *(uint4*)dst = *(uint4*)&buf[0];
    *(uint4*)(dst + 8) = *(uint4*)&buf[8];
}

// ---------------------------------------------------------------------------
// R14: dual-projection GEMM, M-tile 32 (was 64). Grid (16,64)=1024 blocks ->
// 4 blocks/CU (LDS 40KB), doubling occupancy of the dominant stage.
// Each block: 32 rows x 64 cols of BOTH matrices; KV blocks own ONE chunk.
// ---------------------------------------------------------------------------
__global__ __launch_bounds__(256) void k_g0b(
    const ushort* __restrict__ A, const ushort* __restrict__ WtAll,
    const float* __restrict__ bg,
    ushort* __restrict__ Qg, ushort* __restrict__ Kg,
    ushort* __restrict__ Vg, ushort* __restrict__ Gg,
    ushort* __restrict__ Sst, float* __restrict__ Zst)
{
    __shared__ union {
        struct { ushort As[2][2048]; ushort Bs[2][8192]; } s;   // 40 KB
        struct { ushort KcT[64 * 40]; ushort KsT[64 * 40];
                 ushort VT[64 * 40];                            // [col][t] t<32
                 ushort KR[32 * 72]; ushort VR[32 * 72]; } e;   // 24.6 KB
    } sm;
    __shared__ float cosR[32], sinR[32];

    const int tid = threadIdx.x;
    const int ct = blockIdx.x;               // 0..15
    const int rowBase = blockIdx.y * 32;     // 0..2016
    const bool isKV = (ct >= 8);
    const int matCol = (ct & 7) * 64;
    const ushort* __restrict__ B0 = WtAll + (size_t)(isKV ? 1 : 0) * 262144;
    const ushort* __restrict__ B1 = WtAll + (size_t)(isKV ? 2 : 3) * 262144;

    const int wave = tid >> 6, lane = tid & 63;
    const int q = lane >> 4, ln = lane & 15;
    const int nB = wave * 16;                // wave's 16-col slice

    // --- staging addresses ---
    int fA;
    const ushort* gA;
    {
        int f = tid * 8;
        int r = f >> 6;                      // 0..31
        int gc = ((f >> 3) & 7) ^ (r & 7);
        fA = f;
        gA = A + (size_t)(rowBase + r) * 512 + gc * 8;
    }
    int fB[2];
    const ushort* gB0[2];
    const ushort* gB1[2];
#pragma unroll
    for (int u = 0; u < 2; u++) {
        int f = tid * 8 + u * 2048;
        int r = f >> 6;                      // 0..63
        int gc = ((f >> 3) & 7) ^ (r & 7);
        fB[u] = f;
        gB0[u] = B0 + (size_t)(matCol + r) * 512 + gc * 8;
        gB1[u] = B1 + (size_t)(matCol + r) * 512 + gc * 8;
    }

    f32x4 accA[2], accB[2];
#pragma unroll
    for (int i = 0; i < 2; i++) {
        accA[i] = (f32x4){0.f, 0.f, 0.f, 0.f};
        accB[i] = (f32x4){0.f, 0.f, 0.f, 0.f};
    }

    int aoff[2][2], boff[2];
#pragma unroll
    for (int i = 0; i < 2; i++) {
        int ra = i * 16 + ln;
#pragma unroll
        for (int ks = 0; ks < 2; ks++)
            aoff[i][ks] = ra * 64 + (((ks * 4 + q) ^ (ra & 7)) * 8);
    }
    {
        int rb = nB + ln;
#pragma unroll
        for (int ks = 0; ks < 2; ks++)
            boff[ks] = rb * 64 + (((ks * 4 + q) ^ (rb & 7)) * 8);
    }

    async16(&sm.s.As[0][fA], gA);
#pragma unroll
    for (int u = 0; u < 2; u++) {
        async16(&sm.s.Bs[0][fB[u]], gB0[u]);
        async16(&sm.s.Bs[0][4096 + fB[u]], gB1[u]);
    }

    int cur = 0;
    for (int kb = 0; kb < 512; kb += 64) {
        __syncthreads();
        if (kb + 64 < 512) {
            int nxt = cur ^ 1;
            async16(&sm.s.As[nxt][fA], gA + kb + 64);
#pragma unroll
            for (int u = 0; u < 2; u++) {
                async16(&sm.s.Bs[nxt][fB[u]], gB0[u] + kb + 64);
                async16(&sm.s.Bs[nxt][4096 + fB[u]], gB1[u] + kb + 64);
            }
        }
#pragma unroll
        for (int ks = 0; ks < 2; ks++) {
            s16x8 af[2];
#pragma unroll
            for (int i = 0; i < 2; i++)
                af[i] = *(const s16x8*)&sm.s.As[cur][aoff[i][ks]];
            s16x8 b0f = *(const s16x8*)&sm.s.Bs[cur][boff[ks]];
            s16x8 b1f = *(const s16x8*)&sm.s.Bs[cur][4096 + boff[ks]];
#pragma unroll
            for (int i = 0; i < 2; i++) {
                accA[i] = __builtin_amdgcn_mfma_f32_16x16x32_bf16(
                    af[i], b0f, accA[i], 0, 0, 0);
                accB[i] = __builtin_amdgcn_mfma_f32_16x16x32_bf16(
                    af[i], b1f, accB[i], 0, 0, 0);
            }
        }
        cur ^= 1;
    }
    // 32-entry row trig table (KV only)
    if (isKV && tid < 32) {
        float a = (float)((rowBase + tid) & 1023) * PI_OVER_2T;
        cosR[tid] = cosf(a);
        sinR[tid] = sinf(a);
    }
    __syncthreads();

    if (!isKV) {
        ushort* QT = sm.e.KcT;   // reused as [32][72]
        ushort* GT = sm.e.KsT;
        const int colL = nB + ln;
        const float bgv = bg[matCol + colL];
#pragma unroll
        for (int i = 0; i < 2; i++)
#pragma unroll
            for (int r = 0; r < 4; r++) {
                int rowL = i * 16 + q * 4 + r;
                QT[rowL * 72 + colL] = f2bf(fmaxf(accA[i][r], 0.f));
                GT[rowL * 72 + colL] =
                    f2bf(1.f / (1.f + expf(-(accB[i][r] + bgv))));
            }
        __syncthreads();
        {
            int row = tid >> 3, sub = tid & 7;
            uint4 qv = *(const uint4*)&QT[row * 72 + sub * 8];
            uint4 gv = *(const uint4*)&GT[row * 72 + sub * 8];
            size_t go = (size_t)(rowBase + row) * 512 + matCol + sub * 8;
            *(uint4*)&Qg[go] = qv;
            *(uint4*)&Gg[go] = gv;
        }
        return;
    }

    // ---- KV epilogue: exactly ONE chunk per block ----
    const int h = ct - 8;
    const int b = rowBase >> 10;
    const int gG = (rowBase & 1023) >> 5;
    const int blk = (b * 8 + h) * 32 + gG;
    const int col = nB + ln;

    float zc = 0.f, zs = 0.f;
#pragma unroll
    for (int i = 0; i < 2; i++)
#pragma unroll
        for (int r = 0; r < 4; r++) {
            int tLoc = i * 16 + q * 4 + r;
            float ca = cosR[tLoc], sa = sinR[tLoc];
            float kv = fmaxf(accA[i][r], 0.f);
            float vv = accB[i][r];
            sm.e.KR[tLoc * 72 + col] = f2bf(kv);
            sm.e.VR[tLoc * 72 + col] = f2bf(vv);
            float kc = kv * ca, ks_ = kv * sa;
            sm.e.KcT[col * 40 + tLoc] = f2bf(kc);
            sm.e.KsT[col * 40 + tLoc] = f2bf(ks_);
            sm.e.VT [col * 40 + tLoc] = f2bf(vv);
            zc += kc; zs += ks_;
        }
    zc += __shfl_xor(zc, 16); zc += __shfl_xor(zc, 32);
    zs += __shfl_xor(zs, 16); zs += __shfl_xor(zs, 32);
    if (q == 0) {
        Zst[(size_t)blk * 128 + col] = zc;
        Zst[(size_t)blk * 128 + 64 + col] = zs;
    }
    __syncthreads();

    // Coalesced Kg/Vg stores
    {
        int row = tid >> 3, sub = tid & 7;
        uint4 kv4 = *(const uint4*)&sm.e.KR[row * 72 + sub * 8];
        uint4 vv4 = *(const uint4*)&sm.e.VR[row * 72 + sub * 8];
        size_t go = (size_t)(rowBase + row) * 512 + h * 64 + sub * 8;
        *(uint4*)&Kg[go] = kv4;
        *(uint4*)&Vg[go] = vv4;
    }

    // Per-chunk S-state: Sc[e][d] = sum_t V[t][e]*Kc[t][d] (K=32)
    {
        ushort* Sp = Sst + (size_t)blk * 8192;
        s16x8 av = *(const s16x8*)&sm.e.VT[(wave * 16 + ln) * 40 + q * 8];
#pragma unroll
        for (int fj = 0; fj < 4; fj++) {
            s16x8 bc = *(const s16x8*)&sm.e.KcT[(fj * 16 + ln) * 40 + q * 8];
            s16x8 bs = *(const s16x8*)&sm.e.KsT[(fj * 16 + ln) * 40 + q * 8];
            f32x4 sc = __builtin_amdgcn_mfma_f32_16x16x32_bf16(
                av, bc, (f32x4){0.f, 0.f, 0.f, 0.f}, 0, 0, 0);
            f32x4 ss = __builtin_amdgcn_mfma_f32_16x16x32_bf16(
                av, bs, (f32x4){0.f, 0.f, 0.f, 0.f}, 0, 0, 0);
#pragma unroll
            for (int rr = 0; rr < 4; rr++) {
                int e = wave * 16 + q * 4 + rr;
                int d = fj * 16 + ln;
                Sp[e * 64 + d] = f2bf(sc[rr]);
                Sp[4096 + e * 64 + d] = f2bf(ss[rr]);
            }
        }
    }
}

// ---------------------------------------------------------------------------
// R14: segmented chunk-scan. Each 32-long chain split across 4 adjacent
// lanes (8 chunks each); exclusive offset via __shfl_up(width=4).
// 133120 threads = 520 blocks (was 130).
// ---------------------------------------------------------------------------
__global__ __launch_bounds__(256) void k_scan2(
    ushort* __restrict__ Sst, float* __restrict__ Zst)
{
    int id = blockIdx.x * 256 + threadIdx.x;
    if (id < 131072) {
        int chain = id >> 2, s = id & 3;
        int bh = chain >> 11, i4 = (chain & 2047) * 4;
        size_t base = (size_t)bh * (G_ * 8192) + i4 + (size_t)(s * 8) * 8192;
        ushort4 v[8];
#pragma unroll
        for (int k = 0; k < 8; k++)
            v[k] = *(const ushort4*)&Sst[base + (size_t)k * 8192];
        float sx = 0.f, sy = 0.f, sz = 0.f, sw = 0.f;
#pragma unroll
        for (int k = 0; k < 8; k++) {
            sx += bf2f(v[k].x); sy += bf2f(v[k].y);
            sz += bf2f(v[k].z); sw += bf2f(v[k].w);
        }
        float px = 0.f, py = 0.f, pz = 0.f, pw = 0.f;
#pragma unroll
        for (int d = 1; d < 4; d++) {
            float tx = __shfl_up(sx, d, 4);
            float ty = __shfl_up(sy, d, 4);
            float tz = __shfl_up(sz, d, 4);
            float tw = __shfl_up(sw, d, 4);
            if (s >= d) { px += tx; py += ty; pz += tz; pw += tw; }
        }
        float rx = px, ry = py, rz = pz, rw = pw;
#pragma unroll
        for (int k = 0; k < 8; k++) {
            ushort4 t = v[k];
            ushort4 o;
            o.x = f2bf(rx); o.y = f2bf(ry); o.z = f2bf(rz); o.w = f2bf(rw);
            *(ushort4*)&Sst[base + (size_t)k * 8192] = o;
            rx += bf2f(t.x); ry += bf2f(t.y);
            rz += bf2f(t.z); rw += bf2f(t.w);
        }
    } else if (id < 133120) {
        int u = id - 131072;
        int chain = u >> 2, s = u & 3;
        int bh = chain >> 5, i4 = (chain & 31) * 4;
        size_t base = (size_t)bh * (G_ * 128) + i4 + (size_t)(s * 8) * 128;
        float4 v[8];
#pragma unroll
        for (int k = 0; k < 8; k++)
            v[k] = *(const float4*)&Zst[base + (size_t)k * 128];
        float4 sg = make_float4(0.f, 0.f, 0.f, 0.f);
#pragma unroll
        for (int k = 0; k < 8; k++) {
            sg.x += v[k].x; sg.y += v[k].y; sg.z += v[k].z; sg.w += v[k].w;
        }
        float4 p = make_float4(0.f, 0.f, 0.f, 0.f);
#pragma unroll
        for (int d = 1; d < 4; d++) {
            float tx = __shfl_up(sg.x, d, 4);
            float ty = __shfl_up(sg.y, d, 4);
            float tz = __shfl_up(sg.z, d, 4);
            float tw = __shfl_up(sg.w, d, 4);
            if (s >= d) { p.x += tx; p.y += ty; p.z += tz; p.w += tw; }
        }
        float4 run = p;
#pragma unroll
        for (int k = 0; k < 8; k++) {
            float4 t = v[k];
            *(float4*)&Zst[base + (size_t)k * 128] = run;
            run.x += t.x; run.y += t.y; run.z += t.z; run.w += t.w;
        }
    }
}

// ---------------------------------------------------------------------------
// Per-chunk output via MFMA (unchanged, passing).
// ---------------------------------------------------------------------------
__global__ __launch_bounds__(256) void k_out_chunk(
    const ushort* __restrict__ Qg, const ushort* __restrict__ Kg,
    const ushort* __restrict__ Vg, const ushort* __restrict__ Gg,
    const ushort* __restrict__ Sst, const float* __restrict__ Zst,
    ushort* __restrict__ Op)
{
    __shared__ ushort VT[64 * 40];
    __shared__ ushort Pb[32 * 40];
    __shared__ float zinv[32];
    __shared__ float Ot[32 * 68];

    const int blk = blockIdx.x;
    const int bh = blk >> 5, g = blk & 31;
    const int b = bh >> 3, h = bh & 7;
    const int tid = threadIdx.x;
    const int rBase = b * T_ + g * C_;
    const int colB = h * DK_;
    const int wave = tid >> 6, lane = tid & 63;
    const int q = lane >> 4, ln = lane & 15;

    {
        int row = tid >> 3, c8 = (tid & 7) * 8;
        uint4 vraw = *(const uint4*)&Vg[(size_t)(rBase + row) * D_ + colB + c8];
        const ushort* vp = (const ushort*)&vraw;
#pragma unroll
        for (int u = 0; u < 8; u++) VT[(c8 + u) * 40 + row] = vp[u];
    }

    const int mi = wave >> 1, njp = wave & 1;
    const ushort* qrow = Qg + (size_t)(rBase + mi * 16 + ln) * D_ + colB;
    s16x8 aq0 = *(const s16x8*)&qrow[q * 8];
    s16x8 aq1 = *(const s16x8*)&qrow[32 + q * 8];
    {
        const ushort* krow = Kg + (size_t)(rBase + njp * 16 + ln) * D_ + colB;
        s16x8 bk0 = *(const s16x8*)&krow[q * 8];
        s16x8 bk1 = *(const s16x8*)&krow[32 + q * 8];
        f32x4 pacc = __builtin_amdgcn_mfma_f32_16x16x32_bf16(
            aq0, bk0, (f32x4){0.f, 0.f, 0.f, 0.f}, 0, 0, 0);
        pacc = __builtin_amdgcn_mfma_f32_16x16x32_bf16(aq1, bk1, pacc, 0, 0, 0);
        int sl = njp * 16 + ln;
#pragma unroll
        for (int r = 0; r < 4; r++) {
            int tl = mi * 16 + q * 4 + r;
            float w = (sl <= tl) ? cosf((float)(tl - sl) * PI_OVER_2T) : 0.f;
            Pb[tl * 40 + sl] = f2bf(pacc[r] * w);
        }
    }
    __syncthreads();

    {
        int t = tid >> 3, sub = tid & 7;
        uint4 qraw = *(const uint4*)&Qg[(size_t)(rBase + t) * D_ + colB + sub * 8];
        const ushort* qp = (const ushort*)&qraw;
        const float* zcp = Zst + (size_t)blk * 128 + sub * 8;
        float4 zc0 = *(const float4*)&zcp[0];
        float4 zc1 = *(const float4*)&zcp[4];
        float4 zs0 = *(const float4*)&zcp[64];
        float4 zs1 = *(const float4*)&zcp[68];
        float pc = 0.f, ps = 0.f;
        float zcv[8] = {zc0.x, zc0.y, zc0.z, zc0.w, zc1.x, zc1.y, zc1.z, zc1.w};
        float zsv[8] = {zs0.x, zs0.y, zs0.z, zs0.w, zs1.x, zs1.y, zs1.z, zs1.w};
#pragma unroll
        for (int u = 0; u < 8; u++) {
            float qf = bf2f(qp[u]);
            pc += qf * zcv[u]; ps += qf * zsv[u];
        }
        float pr = 0.f;
#pragma unroll
        for (int u = 0; u < 4; u++) pr += bf2f(Pb[t * 40 + sub * 4 + u]);
#pragma unroll
        for (int m = 1; m < 8; m <<= 1) {
            pc += __shfl_xor(pc, m);
            ps += __shfl_xor(ps, m);
            pr += __shfl_xor(pr, m);
        }
        if (sub == 0) {
            float at = (float)(g * C_ + t) * PI_OVER_2T;
            float z = cosf(at) * pc + sinf(at) * ps + pr;
            zinv[t] = 1.f / fmaxf(z, 1e-6f);
        }
    }
    __syncthreads();

    {
        float cr[4], sr[4];
#pragma unroll
        for (int r = 0; r < 4; r++) {
            int tl = mi * 16 + q * 4 + r;
            float at = (float)(g * C_ + tl) * PI_OVER_2T;
            cr[r] = cosf(at); sr[r] = sinf(at);
        }
        s16x8 pf = *(const s16x8*)&Pb[(mi * 16 + ln) * 40 + q * 8];
        const ushort* Sp = Sst + (size_t)blk * 8192;
#pragma unroll
        for (int jj = 0; jj < 2; jj++) {
            int nj = 2 * (wave & 1) + jj;
            const ushort* scp = Sp + (nj * 16 + ln) * 64;
            s16x8 bc0 = *(const s16x8*)&scp[q * 8];
            s16x8 bc1 = *(const s16x8*)&scp[32 + q * 8];
            s16x8 bs0 = *(const s16x8*)&scp[4096 + q * 8];
            s16x8 bs1 = *(const s16x8*)&scp[4096 + 32 + q * 8];
            s16x8 bv  = *(const s16x8*)&VT[(nj * 16 + ln) * 40 + q * 8];
            f32x4 accP = __builtin_amdgcn_mfma_f32_16x16x32_bf16(
                pf, bv, (f32x4){0.f, 0.f, 0.f, 0.f}, 0, 0, 0);
            f32x4 accC = __builtin_amdgcn_mfma_f32_16x16x32_bf16(
                aq0, bc0, (f32x4){0.f, 0.f, 0.f, 0.f}, 0, 0, 0);
            accC = __builtin_amdgcn_mfma_f32_16x16x32_bf16(aq1, bc1, accC, 0, 0, 0);
            f32x4 accS = __builtin_amdgcn_mfma_f32_16x16x32_bf16(
                aq0, bs0, (f32x4){0.f, 0.f, 0.f, 0.f}, 0, 0, 0);
            accS = __builtin_amdgcn_mfma_f32_16x16x32_bf16(aq1, bs1, accS, 0, 0, 0);
#pragma unroll
            for (int r = 0; r < 4; r++) {
                int tl = mi * 16 + q * 4 + r;
                Ot[tl * 68 + nj * 16 + ln] =
                    (accP[r] + cr[r] * accC[r] + sr[r] * accS[r]) * zinv[tl];
            }
        }
    }
    __syncthreads();

    {
        int t = tid >> 3, sub = tid & 7;
        size_t go = (size_t)(rBase + t) * D_ + colB + sub * 8;
        uint4 graw = *(const uint4*)&Gg[go];
        const ushort* gp = (const ushort*)&graw;
        const float* op = &Ot[t * 68 + sub * 8];
        ushort buf[8];
#pragma unroll
        for (int u = 0; u < 8; u++)
            buf[u] = f2bf(op[u] * bf2f(gp[u]));
        *(uint4*)&Op[go] = *(uint4*)&buf[0];
    }
}

// ---------------------------------------------------------------------------
// R14: out-projection GEMM, 32x32 tile, grid (16,64)=1024 blocks.
// ---------------------------------------------------------------------------
__global__ __launch_bounds__(256) void k_gemm2(
    const ushort* __restrict__ A, const ushort* __restrict__ Bt,
    float* __restrict__ Out)
{
    __shared__ ushort As[2][2048];
    __shared__ ushort Bs[2][2048];

    const int tid = threadIdx.x;
    const int matCol = blockIdx.x * 32;
    const int rowBase = blockIdx.y * 32;
    const int wave = tid >> 6, lane = tid & 63;
    const int q = lane >> 4, ln = lane & 15;
    const int mB = (wave >> 1) * 16, nB = (wave & 1) * 16;

    int fA;
    const ushort* gA;
    const ushort* gB;
    {
        int f = tid * 8;
        int r = f >> 6;
        int gc = ((f >> 3) & 7) ^ (r & 7);
        fA = f;
        gA = A  + (size_t)(rowBase + r) * 512 + gc * 8;
        gB = Bt + (size_t)(matCol + r) * 512 + gc * 8;
    }

    f32x4 acc = (f32x4){0.f, 0.f, 0.f, 0.f};
    int aoff[2], boff[2];
    {
        int ra = mB + ln;
        int rb = nB + ln;
#pragma unroll
        for (int ks = 0; ks < 2; ks++) {
            aoff[ks] = ra * 64 + (((ks * 4 + q) ^ (ra & 7)) * 8);
            boff[ks] = rb * 64 + (((ks * 4 + q) ^ (rb & 7)) * 8);
        }
    }

    async16(&As[0][fA], gA);
    async16(&Bs[0][fA], gB);

    int cur = 0;
    for (int kb = 0; kb < 512; kb += 64) {
        __syncthreads();
        if (kb + 64 < 512) {
            async16(&As[cur ^ 1][fA], gA + kb + 64);
            async16(&Bs[cur ^ 1][fA], gB + kb + 64);
        }
#pragma unroll
        for (int ks = 0; ks < 2; ks++) {
            s16x8 af = *(const s16x8*)&As[cur][aoff[ks]];
            s16x8 bf = *(const s16x8*)&Bs[cur][boff[ks]];
            acc = __builtin_amdgcn_mfma_f32_16x16x32_bf16(af, bf, acc, 0, 0, 0);
        }
        cur ^= 1;
    }
    __syncthreads();

    // LDS bounce: 32x32 f32 (pad 36), coalesced float4 stores.
    float* Ot = (float*)&As[0][0];   // 32*36*4 = 4608 B <= 8192 B
#pragma unroll
    for (int r = 0; r < 4; r++)
        Ot[(mB + q * 4 + r) * 36 + nB + ln] = acc[r];
    __syncthreads();

    {
        int row = tid >> 3, sub = tid & 7;
        float4 a0 = *(const float4*)&Ot[row * 36 + sub * 4];
        size_t go = (size_t)(rowBase + row) * 512 + matCol + sub * 4;
        *(float4*)&Out[go] = a0;
    }
}

// ---------------------------------------------------------------------------
extern "C" void kernel_launch(void* const* d_in, const int* in_sizes, int n_in,
                              void* d_out, int out_size, void* d_ws, size_t ws_size,
                              hipStream_t stream)
{
    const float* x  = (const float*)d_in[0];
    const float* Wq = (const float*)d_in[1];
    const float* Wk = (const float*)d_in[2];
    const float* Wv = (const float*)d_in[3];
    const float* Wo = (const float*)d_in[4];
    const float* Wg = (const float*)d_in[5];
    const float* bg = (const float*)d_in[6];
    float* out = (float*)d_out;

    ushort* wsu = (ushort*)d_ws;
    ushort* xb    = wsu;                   // 1M bf16
    ushort* WtAll = xb + 1048576;          // 5*256K bf16
    ushort* Qg    = WtAll + 1310720;       // 1M bf16 each
    ushort* Kg    = Qg + 1048576;
    ushort* Vg    = Kg + 1048576;
    ushort* Gg    = Vg + 1048576;
    ushort* Sst   = Gg + 1048576;          // 4M bf16
    ushort* Opb   = Sst + 4194304;         // 1M bf16
    float*  Zst   = (float*)(Opb + 1048576);  // 64K f32

    dim3 blk(256);
    k_conv<<<dim3(1344), blk, 0, stream>>>(x, Wq, Wk, Wv, Wg, Wo, xb, WtAll);
    k_g0b<<<dim3(16, 64), blk, 0, stream>>>(
        xb, WtAll, bg, Qg, Kg, Vg, Gg, Sst, Zst);
    k_scan2<<<dim3(520), blk, 0, stream>>>(Sst, Zst);
    k_out_chunk<<<dim3(NBH_ * G_), blk, 0, stream>>>(
        Qg, Kg, Vg, Gg, Sst, Zst, Opb);
    k_gemm2<<<dim3(16, 64), blk, 0, stream>>>(
        Opb, WtAll + (size_t)4 * 262144, out);
}